// Round 2
// baseline (547.288 us; speedup 1.0000x reference)
//
#include <hip/hip_runtime.h>
#include <hip/hip_bf16.h>

// CrossNetMix: B=16384, D=1024, R=64, E=4, L=3
// Per layer (row-local!):  g = softmax(xl @ Gw^T)            [B,4]
//   h  = tanh(xl @ V^T)                                      [B,256]   (V as [256,1024])
//   t2 = tanh(C @ h)  per expert                             [B,256]
//   w  = g_e * t2                                            [B,256]
//   xl += x0 * (bias + w @ Umat)   where Umat[e*64+r][d] = U[e][d][r]
// (uses sum_e g_e == 1 to fold bias)
//
// R2: BM=16, 4 waves, 1024 blocks -> 4 blocks/CU for latency hiding
// (R1 was BM=64 -> 256 blocks = 1 block/CU, Occupancy 21%, all pipes idle).

using bf16x8 = __attribute__((ext_vector_type(8))) short;
using f32x4  = __attribute__((ext_vector_type(4))) float;

__device__ __forceinline__ unsigned short f2bf(float f) {
  union { __hip_bfloat16 h; unsigned short s; } u;
  u.h = __float2bfloat16(f);   // RNE
  return u.s;
}
__device__ __forceinline__ unsigned int pk2(float a, float b) {
  return (unsigned int)f2bf(a) | ((unsigned int)f2bf(b) << 16);
}
__device__ __forceinline__ float fast_tanh(float x) {
  float cx = fminf(15.0f, fmaxf(-15.0f, x));
  float t = exp2f(cx * 2.885390081777927f);   // e^(2x)
  return (t - 1.0f) / (t + 1.0f);
}

// ---- convert fp32 weights -> bf16 workspace (vectorized, runs every call)
__global__ void preconvert_k(const float4* __restrict__ V4, const float4* __restrict__ U4,
                             const float4* __restrict__ C4, const float4* __restrict__ G4,
                             ushort4* __restrict__ Vb4, ushort4* __restrict__ Ub4,
                             ushort4* __restrict__ Cb4, ushort4* __restrict__ Gb4) {
  int i = blockIdx.x * 256 + threadIdx.x;
  if (i < 196608) {               // L*E*R*D/4 == L*E*D*R/4
    float4 v = V4[i], u = U4[i];
    ushort4 ov, ou;
    ov.x = f2bf(v.x); ov.y = f2bf(v.y); ov.z = f2bf(v.z); ov.w = f2bf(v.w);
    ou.x = f2bf(u.x); ou.y = f2bf(u.y); ou.z = f2bf(u.z); ou.w = f2bf(u.w);
    Vb4[i] = ov; Ub4[i] = ou;
  }
  if (i < 12288) {                // L*E*R*R/4
    float4 c = C4[i];
    ushort4 oc; oc.x = f2bf(c.x); oc.y = f2bf(c.y); oc.z = f2bf(c.z); oc.w = f2bf(c.w);
    Cb4[i] = oc;
  }
  if (i < 1024) {                 // E*D/4
    float4 g = G4[i];
    ushort4 og; og.x = f2bf(g.x); og.y = f2bf(g.y); og.z = f2bf(g.z); og.w = f2bf(g.w);
    Gb4[i] = og;
  }
}

// ---- one layer, BM=16 rows per block, 4 waves (256 thr), 1024 blocks
__global__ __launch_bounds__(256, 4)
void crossmix_layer(const float* __restrict__ xl_in, float* __restrict__ xl_out,
                    const float* __restrict__ x0,
                    const unsigned short* __restrict__ Vb,   // [256][1024]
                    const unsigned short* __restrict__ Ub,   // [E][D][R]
                    const unsigned short* __restrict__ Cb,   // [E][R][R]
                    const unsigned short* __restrict__ Gb,   // [E][D]
                    const float* __restrict__ bias) {        // [D]
  constexpr int BM = 16, DD = 1024, BK = 128;
  __shared__ unsigned short xlbuf[2][BM * BK];   // 2x4KB, XOR-swizzled bf16 xl chunks
  __shared__ unsigned short tbuf[BM * 256];      // 8KB, swizzled; holds t then w
  __shared__ float g_lds[BM][4];                 // gate logits -> softmax g

  const int tid  = threadIdx.x;
  const int lane = tid & 63;
  const int wave = tid >> 6;          // 0..3
  const int l15  = lane & 15;
  const int l4   = lane >> 4;         // 0..3
  const int rowbase = blockIdx.x * BM;

  // -------- staging: 16 rows x 128 cols fp32 -> bf16 LDS (issue early / write late)
  float4 sv[2];
  auto stage_load = [&](int c) {
    int r = tid >> 4, cb = (tid & 15) * 8;
    const float* s = xl_in + (size_t)(rowbase + r) * DD + c * BK + cb;
    sv[0] = *(const float4*)(s);
    sv[1] = *(const float4*)(s + 4);
  };
  auto stage_write = [&](int buf) {
    int r = tid >> 4, cb = (tid & 15) * 8;
    uint4 p = make_uint4(pk2(sv[0].x, sv[0].y), pk2(sv[0].z, sv[0].w),
                         pk2(sv[1].x, sv[1].y), pk2(sv[1].z, sv[1].w));
    char* lb = (char*)xlbuf[buf];
    *(uint4*)(lb + ((r * 256 + cb * 2) ^ ((r & 7) << 4))) = p;
  };

  // ================= G1: h = xl @ V^T  (+ gate logits on wave 0) ==========
  f32x4 zf = {0.f, 0.f, 0.f, 0.f};
  f32x4 acc1[4], accg;
  #pragma unroll
  for (int n = 0; n < 4; ++n) acc1[n] = zf;
  accg = zf;
  const int ncol = wave * 64;   // this wave's G1 output columns (er-space)

  stage_load(0); stage_write(0);
  __syncthreads();
  for (int c = 0; c < 8; ++c) {
    if (c < 7) stage_load(c + 1);          // issue loads early
    const char* lb = (const char*)xlbuf[c & 1];
    #pragma unroll
    for (int ki = 0; ki < 4; ++ki) {
      bf16x8 afr = *(const bf16x8*)(lb + ((l15 * 256 + ki * 64 + l4 * 16) ^ ((l15 & 7) << 4)));
      int kg = c * 128 + ki * 32 + l4 * 8;
      #pragma unroll
      for (int nt = 0; nt < 4; ++nt) {
        bf16x8 bfr = *(const bf16x8*)(Vb + (ncol + nt * 16 + l15) * 1024 + kg);
        acc1[nt] = __builtin_amdgcn_mfma_f32_16x16x32_bf16(afr, bfr, acc1[nt], 0, 0, 0);
      }
      if (wave == 0) {   // gate logits as an extra N-tile (cols 0..3 real, rest zero)
        bf16x8 gfr = {0, 0, 0, 0, 0, 0, 0, 0};
        if (l15 < 4) gfr = *(const bf16x8*)(Gb + l15 * 1024 + kg);
        accg = __builtin_amdgcn_mfma_f32_16x16x32_bf16(afr, gfr, accg, 0, 0, 0);
      }
    }
    if (c < 7) stage_write((c + 1) & 1);   // cvt+LDS write after compute
    __syncthreads();
  }

  // gate logits -> LDS ; t = tanh(h) -> tbuf (swizzled)
  if (wave == 0 && l15 < 4) {
    #pragma unroll
    for (int rg = 0; rg < 4; ++rg)
      g_lds[l4 * 4 + rg][l15] = accg[rg];
  }
  #pragma unroll
  for (int nt = 0; nt < 4; ++nt) {
    int col = ncol + nt * 16 + l15;
    #pragma unroll
    for (int rg = 0; rg < 4; ++rg) {
      int row = l4 * 4 + rg;
      *(unsigned short*)((char*)tbuf + ((row * 512 + col * 2) ^ ((row & 7) << 4)))
          = f2bf(fast_tanh(acc1[nt][rg]));
    }
  }
  __syncthreads();

  // softmax over 4 experts, one thread per row
  if (tid < BM) {
    float a0 = g_lds[tid][0], a1 = g_lds[tid][1], a2 = g_lds[tid][2], a3 = g_lds[tid][3];
    float mx = fmaxf(fmaxf(a0, a1), fmaxf(a2, a3));
    float e0 = exp2f((a0 - mx) * 1.442695041f);
    float e1 = exp2f((a1 - mx) * 1.442695041f);
    float e2 = exp2f((a2 - mx) * 1.442695041f);
    float e3 = exp2f((a3 - mx) * 1.442695041f);
    float inv = 1.0f / (e0 + e1 + e2 + e3);
    g_lds[tid][0] = e0 * inv; g_lds[tid][1] = e1 * inv;
    g_lds[tid][2] = e2 * inv; g_lds[tid][3] = e3 * inv;
  }
  __syncthreads();

  // ================= C-mix: t2 = tanh(C@t); w = g*t2 -> tbuf ==============
  const int ex = wave;                // one expert per wave
  f32x4 acc2[4];
  #pragma unroll
  for (int n = 0; n < 4; ++n) acc2[n] = zf;
  #pragma unroll
  for (int ki = 0; ki < 2; ++ki) {
    int kcol = ex * 64 + ki * 32 + l4 * 8;
    bf16x8 afr = *(const bf16x8*)((const char*)tbuf + ((l15 * 512 + kcol * 2) ^ ((l15 & 7) << 4)));
    #pragma unroll
    for (int nt = 0; nt < 4; ++nt) {
      bf16x8 bfr = *(const bf16x8*)(Cb + ex * 4096 + (nt * 16 + l15) * 64 + ki * 32 + l4 * 8);
      acc2[nt] = __builtin_amdgcn_mfma_f32_16x16x32_bf16(afr, bfr, acc2[nt], 0, 0, 0);
    }
  }
  __syncthreads();   // all reads of t done before overwriting tbuf with w
  #pragma unroll
  for (int nt = 0; nt < 4; ++nt) {
    int col = ex * 64 + nt * 16 + l15;
    #pragma unroll
    for (int rg = 0; rg < 4; ++rg) {
      int row = l4 * 4 + rg;
      float gv = g_lds[row][ex];
      *(unsigned short*)((char*)tbuf + ((row * 512 + col * 2) ^ ((row & 7) << 4)))
          = f2bf(gv * fast_tanh(acc2[nt][rg]));
    }
  }
  __syncthreads();

  // ================= G2: delta = w @ Umat ; epilogue ======================
  f32x4 acc3[16];
  #pragma unroll
  for (int n = 0; n < 16; ++n) acc3[n] = zf;
  #pragma unroll 2
  for (int ki = 0; ki < 8; ++ki) {
    int kcol = ki * 32 + l4 * 8;
    bf16x8 afr = *(const bf16x8*)((const char*)tbuf + ((l15 * 512 + kcol * 2) ^ ((l15 & 7) << 4)));
    int ee = kcol >> 6, rr = kcol & 63;
    #pragma unroll
    for (int nt = 0; nt < 16; ++nt) {
      int d = wave * 256 + nt * 16 + l15;
      bf16x8 bfr = *(const bf16x8*)(Ub + ee * 65536 + d * 64 + rr);  // U[e][d][r]
      acc3[nt] = __builtin_amdgcn_mfma_f32_16x16x32_bf16(afr, bfr, acc3[nt], 0, 0, 0);
    }
  }
  // epilogue: xl_out = xl_in + x0*(bias + delta)   (f32 residual path)
  #pragma unroll
  for (int nt = 0; nt < 16; ++nt) {
    int d = wave * 256 + nt * 16 + l15;
    float bv = bias[d];
    #pragma unroll
    for (int rg = 0; rg < 4; ++rg) {
      size_t idx = (size_t)(rowbase + l4 * 4 + rg) * DD + d;
      xl_out[idx] = xl_in[idx] + x0[idx] * (bv + acc3[nt][rg]);
    }
  }
}

extern "C" void kernel_launch(void* const* d_in, const int* in_sizes, int n_in,
                              void* d_out, int out_size, void* d_ws, size_t ws_size,
                              hipStream_t stream) {
  const float* x    = (const float*)d_in[0];   // [B,D]
  const float* U    = (const float*)d_in[1];   // [L,E,D,R]
  const float* V    = (const float*)d_in[2];   // [L,E,R,D]
  const float* C    = (const float*)d_in[3];   // [L,E,R,R]
  const float* bias = (const float*)d_in[4];   // [L,D]
  const float* gw   = (const float*)d_in[5];   // [E,D]
  float* out = (float*)d_out;

  // ws: bf16 weights only (~3.25 MB)
  unsigned short* Vb = (unsigned short*)d_ws;  // 786432
  unsigned short* Ub = Vb + 786432;            // 786432
  unsigned short* Cb = Ub + 786432;            // 49152
  unsigned short* Gb = Cb + 49152;             // 4096

  preconvert_k<<<dim3(768), dim3(256), 0, stream>>>(
      (const float4*)V, (const float4*)U, (const float4*)C, (const float4*)gw,
      (ushort4*)Vb, (ushort4*)Ub, (ushort4*)Cb, (ushort4*)Gb);

  // layer 0: x -> out ; layers 1,2: out -> out (in-place is safe: row-local)
  for (int l = 0; l < 3; ++l) {
    const float* xin = (l == 0) ? x : out;
    crossmix_layer<<<dim3(1024), dim3(256), 0, stream>>>(
        xin, out, x,
        Vb + l * 262144, Ub + l * 262144, Cb + l * 16384, Gb,
        bias + l * 1024);
  }
}

// Round 3
// 461.412 us; speedup vs baseline: 1.1861x; 1.1861x over previous
//
#include <hip/hip_runtime.h>
#include <hip/hip_bf16.h>

// CrossNetMix fused: B=16384, D=1024, R=64, E=4, L=3
// Row-local per layer:
//   g  = softmax(xl @ Gw^T)                         [B,4]
//   t  = tanh(xl @ V^T)                             [B,256]
//   w  = g_e * tanh(C @ t)                          [B,256]
//   xl += x0 * (bias + w @ Umat), Umat[e*64+r][d]=U[e][d][r]   (sum_e g_e == 1)
//
// R3: single fused kernel, all 3 layers. xl state in f32 REGISTERS (exact
// residual path), re-encoded to swizzled bf16 LDS tile per layer for G1's
// A-operand. No inter-layer HBM round-trip. 512 blocks x 1024 thr (16 waves),
// 1 block/CU. x0 read f32 from global (L3-resident) to protect accuracy.

using bf16x8 = __attribute__((ext_vector_type(8))) short;
using f32x4  = __attribute__((ext_vector_type(4))) float;

__device__ __forceinline__ unsigned short f2bf(float f) {
  union { __hip_bfloat16 h; unsigned short s; } u;
  u.h = __float2bfloat16(f);   // RNE
  return u.s;
}
__device__ __forceinline__ float fast_tanh(float x) {
  float cx = fminf(15.0f, fmaxf(-15.0f, x));
  float t = exp2f(cx * 2.885390081777927f);   // e^(2x)
  return (t - 1.0f) / (t + 1.0f);
}

// ---- convert fp32 weights -> bf16 workspace (vectorized, runs every call)
__global__ void preconvert_k(const float4* __restrict__ V4, const float4* __restrict__ U4,
                             const float4* __restrict__ C4, const float4* __restrict__ G4,
                             ushort4* __restrict__ Vb4, ushort4* __restrict__ Ub4,
                             ushort4* __restrict__ Cb4, ushort4* __restrict__ Gb4) {
  int i = blockIdx.x * 256 + threadIdx.x;
  if (i < 196608) {               // L*E*R*D/4 == L*E*D*R/4
    float4 v = V4[i], u = U4[i];
    ushort4 ov, ou;
    ov.x = f2bf(v.x); ov.y = f2bf(v.y); ov.z = f2bf(v.z); ov.w = f2bf(v.w);
    ou.x = f2bf(u.x); ou.y = f2bf(u.y); ou.z = f2bf(u.z); ou.w = f2bf(u.w);
    Vb4[i] = ov; Ub4[i] = ou;
  }
  if (i < 12288) {                // L*E*R*R/4
    float4 c = C4[i];
    ushort4 oc; oc.x = f2bf(c.x); oc.y = f2bf(c.y); oc.z = f2bf(c.z); oc.w = f2bf(c.w);
    Cb4[i] = oc;
  }
  if (i < 1024) {                 // E*D/4
    float4 g = G4[i];
    ushort4 og; og.x = f2bf(g.x); og.y = f2bf(g.y); og.z = f2bf(g.z); og.w = f2bf(g.w);
    Gb4[i] = og;
  }
}

// ---- fused 3-layer kernel: BM=32 rows/block, 16 waves (1024 thr), 512 blocks
__global__ __launch_bounds__(1024, 4)
void crossmix_fused(const float* __restrict__ x, float* __restrict__ out,
                    const unsigned short* __restrict__ Vb,   // [L][256][1024]
                    const unsigned short* __restrict__ Ub,   // [L][E][D][R]
                    const unsigned short* __restrict__ Cb,   // [L][E][R][R]
                    const unsigned short* __restrict__ Gb,   // [E][D]
                    const float* __restrict__ bias) {        // [L][D]
  constexpr int BM = 32, DD = 1024;
  __shared__ unsigned short xl_lds[BM * DD];   // 64KB, XOR-swizzled bf16 xl tile
  __shared__ unsigned short tbuf[BM * 256];    // 16KB, swizzled; holds t then w
  __shared__ float g_lds[BM][4];               // gate logits -> softmax g

  const int tid  = threadIdx.x;
  const int lane = tid & 63;
  const int wc   = tid >> 6;          // wave 0..15: owns d-cols wc*64..+64
  const int l15  = lane & 15;
  const int l4   = lane >> 4;         // 0..3
  const size_t rowbase = (size_t)blockIdx.x * BM;

  f32x4 zf = {0.f, 0.f, 0.f, 0.f};

  // xl state: xlr[mt][nt] holds xl[mt*16 + l4*4 + rg][wc*64 + nt*16 + l15]
  f32x4 xlr[2][4];

  // ---- init: load x -> xl regs + bf16 swizzled LDS tile
  #pragma unroll
  for (int mt = 0; mt < 2; ++mt)
    #pragma unroll
    for (int nt = 0; nt < 4; ++nt)
      #pragma unroll
      for (int rg = 0; rg < 4; ++rg) {
        int rowl = mt * 16 + l4 * 4 + rg;
        int d = wc * 64 + nt * 16 + l15;
        float v = x[(rowbase + rowl) * DD + d];
        xlr[mt][nt][rg] = v;
        *(unsigned short*)((char*)xl_lds + ((rowl * 2048 + d * 2) ^ ((rowl & 7) << 4))) = f2bf(v);
      }
  __syncthreads();

  for (int l = 0; l < 3; ++l) {
    const unsigned short* Vl = Vb + l * 262144;
    const unsigned short* Ul = Ub + l * 262144;
    const unsigned short* Cl = Cb + l * 16384;
    const float* bl = bias + l * 1024;

    // ===== G1: t-logits = xl @ V^T (rows 0..31, this wave's 16 cols) =====
    f32x4 acc1[2], accg[2];
    acc1[0] = zf; acc1[1] = zf; accg[0] = zf; accg[1] = zf;
    const int ncol = wc * 16;
    #pragma unroll 4
    for (int ks = 0; ks < 32; ++ks) {
      bf16x8 afr[2];
      #pragma unroll
      for (int mt = 0; mt < 2; ++mt) {
        int row = mt * 16 + l15;
        afr[mt] = *(const bf16x8*)((const char*)xl_lds +
                    ((row * 2048 + ks * 64 + l4 * 16) ^ ((row & 7) << 4)));
      }
      int kg = ks * 32 + l4 * 8;
      bf16x8 bfr = *(const bf16x8*)(Vl + (ncol + l15) * 1024 + kg);
      acc1[0] = __builtin_amdgcn_mfma_f32_16x16x32_bf16(afr[0], bfr, acc1[0], 0, 0, 0);
      acc1[1] = __builtin_amdgcn_mfma_f32_16x16x32_bf16(afr[1], bfr, acc1[1], 0, 0, 0);
      if (wc == 0) {   // gate logits as extra tile (cols 0..3 real, rest zero)
        bf16x8 gfr = {0, 0, 0, 0, 0, 0, 0, 0};
        if (l15 < 4) gfr = *(const bf16x8*)(Gb + l15 * 1024 + kg);
        accg[0] = __builtin_amdgcn_mfma_f32_16x16x32_bf16(afr[0], gfr, accg[0], 0, 0, 0);
        accg[1] = __builtin_amdgcn_mfma_f32_16x16x32_bf16(afr[1], gfr, accg[1], 0, 0, 0);
      }
    }
    // t = tanh -> tbuf (swizzled); wave0: gate logits -> g_lds
    #pragma unroll
    for (int mt = 0; mt < 2; ++mt)
      #pragma unroll
      for (int rg = 0; rg < 4; ++rg) {
        int row = mt * 16 + l4 * 4 + rg;
        int col = ncol + l15;
        *(unsigned short*)((char*)tbuf + ((row * 512 + col * 2) ^ ((row & 7) << 4)))
            = f2bf(fast_tanh(acc1[mt][rg]));
      }
    if (wc == 0 && l15 < 4) {
      #pragma unroll
      for (int mt = 0; mt < 2; ++mt)
        #pragma unroll
        for (int rg = 0; rg < 4; ++rg)
          g_lds[mt * 16 + l4 * 4 + rg][l15] = accg[mt][rg];
    }
    __syncthreads();

    // softmax over 4 experts, one thread per row
    if (tid < BM) {
      float a0 = g_lds[tid][0], a1 = g_lds[tid][1], a2 = g_lds[tid][2], a3 = g_lds[tid][3];
      float mx = fmaxf(fmaxf(a0, a1), fmaxf(a2, a3));
      float e0 = exp2f((a0 - mx) * 1.442695041f);
      float e1 = exp2f((a1 - mx) * 1.442695041f);
      float e2 = exp2f((a2 - mx) * 1.442695041f);
      float e3 = exp2f((a3 - mx) * 1.442695041f);
      float inv = 1.0f / (e0 + e1 + e2 + e3);
      g_lds[tid][0] = e0 * inv; g_lds[tid][1] = e1 * inv;
      g_lds[tid][2] = e2 * inv; g_lds[tid][3] = e3 * inv;
    }

    // ===== C-mix: t2 = C @ t (per expert); this wave: expert wc>>2, quarter wc&3
    const int ex = wc >> 2, q = wc & 3;
    f32x4 acc2[2];
    acc2[0] = zf; acc2[1] = zf;
    #pragma unroll
    for (int ks = 0; ks < 2; ++ks) {
      bf16x8 afr[2];
      #pragma unroll
      for (int mt = 0; mt < 2; ++mt) {
        int row = mt * 16 + l15;
        afr[mt] = *(const bf16x8*)((const char*)tbuf +
                    ((row * 512 + (ex * 64 + ks * 32 + l4 * 8) * 2) ^ ((row & 7) << 4)));
      }
      bf16x8 bfr = *(const bf16x8*)(Cl + ex * 4096 + (q * 16 + l15) * 64 + ks * 32 + l4 * 8);
      acc2[0] = __builtin_amdgcn_mfma_f32_16x16x32_bf16(afr[0], bfr, acc2[0], 0, 0, 0);
      acc2[1] = __builtin_amdgcn_mfma_f32_16x16x32_bf16(afr[1], bfr, acc2[1], 0, 0, 0);
    }
    __syncthreads();   // all t-reads done + softmax visible
    // w = g * tanh(t2) -> tbuf
    #pragma unroll
    for (int mt = 0; mt < 2; ++mt)
      #pragma unroll
      for (int rg = 0; rg < 4; ++rg) {
        int row = mt * 16 + l4 * 4 + rg;
        int col = ex * 64 + q * 16 + l15;
        float gv = g_lds[row][ex];
        *(unsigned short*)((char*)tbuf + ((row * 512 + col * 2) ^ ((row & 7) << 4)))
            = f2bf(gv * fast_tanh(acc2[mt][rg]));
      }
    __syncthreads();

    // ===== G2: delta = w @ Umat (this wave's 64 d-cols) =====
    f32x4 acc3[2][4];
    #pragma unroll
    for (int mt = 0; mt < 2; ++mt)
      #pragma unroll
      for (int nt = 0; nt < 4; ++nt) acc3[mt][nt] = zf;
    #pragma unroll 2
    for (int ks = 0; ks < 8; ++ks) {
      bf16x8 afr[2];
      #pragma unroll
      for (int mt = 0; mt < 2; ++mt) {
        int row = mt * 16 + l15;
        afr[mt] = *(const bf16x8*)((const char*)tbuf +
                    ((row * 512 + (ks * 32 + l4 * 8) * 2) ^ ((row & 7) << 4)));
      }
      int k = ks * 32 + l4 * 8;
      int ee = k >> 6, rr = k & 63;
      #pragma unroll
      for (int nt = 0; nt < 4; ++nt) {
        int d = wc * 64 + nt * 16 + l15;
        bf16x8 bfr = *(const bf16x8*)(Ul + ee * 65536 + d * 64 + rr);  // U[e][d][r]
        acc3[0][nt] = __builtin_amdgcn_mfma_f32_16x16x32_bf16(afr[0], bfr, acc3[0][nt], 0, 0, 0);
        acc3[1][nt] = __builtin_amdgcn_mfma_f32_16x16x32_bf16(afr[1], bfr, acc3[1][nt], 0, 0, 0);
      }
    }

    // epilogue: xl += x0 * (bias + delta)   (f32 residual path; x0 f32 from L3)
    #pragma unroll
    for (int nt = 0; nt < 4; ++nt) {
      int d = wc * 64 + nt * 16 + l15;
      float bv = bl[d];
      #pragma unroll
      for (int mt = 0; mt < 2; ++mt)
        #pragma unroll
        for (int rg = 0; rg < 4; ++rg) {
          int rowl = mt * 16 + l4 * 4 + rg;
          float x0v = x[(rowbase + rowl) * DD + d];
          xlr[mt][nt][rg] += x0v * (bv + acc3[mt][nt][rg]);
        }
    }

    // re-encode xl tile for next layer's G1
    if (l < 2) {
      #pragma unroll
      for (int mt = 0; mt < 2; ++mt)
        #pragma unroll
        for (int nt = 0; nt < 4; ++nt)
          #pragma unroll
          for (int rg = 0; rg < 4; ++rg) {
            int rowl = mt * 16 + l4 * 4 + rg;
            int d = wc * 64 + nt * 16 + l15;
            *(unsigned short*)((char*)xl_lds + ((rowl * 2048 + d * 2) ^ ((rowl & 7) << 4)))
                = f2bf(xlr[mt][nt][rg]);
          }
    }
    __syncthreads();   // tbuf reads done; xl_lds writes visible
  }

  // ---- final store (f32)
  #pragma unroll
  for (int mt = 0; mt < 2; ++mt)
    #pragma unroll
    for (int nt = 0; nt < 4; ++nt)
      #pragma unroll
      for (int rg = 0; rg < 4; ++rg) {
        int rowl = mt * 16 + l4 * 4 + rg;
        int d = wc * 64 + nt * 16 + l15;
        out[(rowbase + rowl) * DD + d] = xlr[mt][nt][rg];
      }
}

extern "C" void kernel_launch(void* const* d_in, const int* in_sizes, int n_in,
                              void* d_out, int out_size, void* d_ws, size_t ws_size,
                              hipStream_t stream) {
  const float* x    = (const float*)d_in[0];   // [B,D]
  const float* U    = (const float*)d_in[1];   // [L,E,D,R]
  const float* V    = (const float*)d_in[2];   // [L,E,R,D]
  const float* C    = (const float*)d_in[3];   // [L,E,R,R]
  const float* bias = (const float*)d_in[4];   // [L,D]
  const float* gw   = (const float*)d_in[5];   // [E,D]
  float* out = (float*)d_out;

  // ws: bf16 weights only (~3.25 MB)
  unsigned short* Vb = (unsigned short*)d_ws;  // 786432
  unsigned short* Ub = Vb + 786432;            // 786432
  unsigned short* Cb = Ub + 786432;            // 49152
  unsigned short* Gb = Cb + 49152;             // 4096

  preconvert_k<<<dim3(768), dim3(256), 0, stream>>>(
      (const float4*)V, (const float4*)U, (const float4*)C, (const float4*)gw,
      (ushort4*)Vb, (ushort4*)Ub, (ushort4*)Cb, (ushort4*)Gb);

  crossmix_fused<<<dim3(512), dim3(1024), 0, stream>>>(
      x, out, Vb, Ub, Cb, Gb, bias);
}